// Round 5
// baseline (163.439 us; speedup 1.0000x reference)
//
#include <hip/hip_runtime.h>

// Problem constants (fixed by reference setup_inputs)
#define N_PRE 8192
#define N_CUR 16384
#define KNN   8

// Workspace layout (bytes):
//   [0,    64K) : c2p  u32[N_CUR]     nearest-pre index per cur point
//   [64K, 192K) : pre4 float4[N_PRE]  (-2px, -2py, -2pz, |p|^2)
//   [192K,448K) : cur4 float4[N_CUR]  ( cx,   cy,   cz,  |c|^2)
//
// Comparator trick: for a fixed query q, ordering by true sqdist equals
// ordering by (|cand|^2 - 2 cand.q)  -> 3 FMA per candidate.
// d can be NEGATIVE -> monotone float->u32 key map on (rare) insert events.

#define MAPPED_INF 0xFF800000u  // monotone key of +inf (empty-slot sentinel)

__device__ __forceinline__ unsigned key_of(float d) {
    unsigned b = __float_as_uint(d);
    return b ^ (0x80000000u | (unsigned)((int)b >> 31));
}
__device__ __forceinline__ float float_of_key(unsigned k) {
    unsigned b = (k & 0x80000000u) ? (k ^ 0x80000000u) : ~k;
    return __uint_as_float(b);
}
__device__ __forceinline__ unsigned shfl_u32(unsigned x, int src) {
    return (unsigned)__shfl((int)x, src);
}
__device__ __forceinline__ unsigned shfl_up1_u32(unsigned x) {
    return (unsigned)__shfl_up((int)x, 1);
}

// ---------- prep: pack comparator-form coords ----------
__global__ __launch_bounds__(256) void prep_kernel(
        const float* __restrict__ pre, const float* __restrict__ cur,
        float4* __restrict__ pre4, float4* __restrict__ cur4) {
    int i = blockIdx.x * 256 + threadIdx.x;
    if (i < N_CUR) {
        float x = cur[i], y = cur[N_CUR + i], z = cur[2 * N_CUR + i];
        cur4[i] = make_float4(x, y, z, fmaf(x, x, fmaf(y, y, z * z)));
    }
    if (i < N_PRE) {
        float x = pre[i], y = pre[N_PRE + i], z = pre[2 * N_PRE + i];
        pre4[i] = make_float4(-2.f * x, -2.f * y, -2.f * z,
                              fmaf(x, x, fmaf(y, y, z * z)));
    }
}

// ---------- Kernel A: cur2pre argmin ----------
// 256-thr blocks (4 waves); wave owns Q=4 cur points; CPL=4 candidates per
// lane per step (4 independent ds_read_b128). Branchless per-lane running
// min (ascending-idx stream -> strict < keeps lowest idx); u64 butterfly
// merge at the end (key<<32|idx -> lowest idx on key ties).
#define TILE_A 2048

__global__ __launch_bounds__(256, 4) void cur2pre_kernel(
        const float4* __restrict__ pre4, const float4* __restrict__ cur4,
        unsigned* __restrict__ c2p) {
    __shared__ float4 sp[TILE_A];
    const int tid  = threadIdx.x;
    const int lane = tid & 63;
    const int w    = tid >> 6;                 // 0..3
    const int j0   = blockIdx.x * 16 + w * 4;  // this wave's 4 cur points

    float4 cq[4];
#pragma unroll
    for (int q = 0; q < 4; ++q) cq[q] = cur4[j0 + q];

    float    bq[4];
    unsigned biq[4];
#pragma unroll
    for (int q = 0; q < 4; ++q) { bq[q] = __int_as_float(0x7F800000); biq[q] = 0u; }

    for (int tile = 0; tile < N_PRE; tile += TILE_A) {
        __syncthreads();
        for (int k = tid; k < TILE_A; k += 256) sp[k] = pre4[tile + k];
        __syncthreads();

        for (int s = 0; s < TILE_A; s += 256) {
            float4 c0 = sp[s +       lane];
            float4 c1 = sp[s +  64 + lane];
            float4 c2 = sp[s + 128 + lane];
            float4 c3 = sp[s + 192 + lane];
            unsigned base = (unsigned)(tile + s + lane);
#pragma unroll
            for (int q = 0; q < 4; ++q) {
                float d0 = fmaf(c0.x, cq[q].x, fmaf(c0.y, cq[q].y, fmaf(c0.z, cq[q].z, c0.w)));
                float d1 = fmaf(c1.x, cq[q].x, fmaf(c1.y, cq[q].y, fmaf(c1.z, cq[q].z, c1.w)));
                float d2 = fmaf(c2.x, cq[q].x, fmaf(c2.y, cq[q].y, fmaf(c2.z, cq[q].z, c2.w)));
                float d3 = fmaf(c3.x, cq[q].x, fmaf(c3.y, cq[q].y, fmaf(c3.z, cq[q].z, c3.w)));
                if (d0 < bq[q]) { bq[q] = d0; biq[q] = base; }
                if (d1 < bq[q]) { bq[q] = d1; biq[q] = base + 64; }
                if (d2 < bq[q]) { bq[q] = d2; biq[q] = base + 128; }
                if (d3 < bq[q]) { bq[q] = d3; biq[q] = base + 192; }
            }
        }
    }

#pragma unroll
    for (int q = 0; q < 4; ++q) {
        unsigned long long v =
            (((unsigned long long)key_of(bq[q])) << 32) | biq[q];
#pragma unroll
        for (int off = 32; off > 0; off >>= 1) {
            unsigned long long o = __shfl_xor((unsigned long long)v, off);
            v = (o < v) ? o : v;
        }
        if (lane == 0) c2p[j0 + q] = (unsigned)(v & 0xFFFFFFFFull);
    }
}

// ---------- Kernel B: per-pre top-8 + masked mean ----------
// 256-thr blocks (4 waves); wave owns P=4 pre points; CPL=4 candidates per
// lane per step. Fast path per step (1024 pair-evals): 4 reads + 48 FMA +
// 12 min + 4 cmp + ONE scalar branch. Event path: per (pre,k) ballots in
// ascending-idx order; shift-insert into lanes-0..7 sorted list.
#define TILE_B 2048

__global__ __launch_bounds__(256, 2) void knn_finalize_kernel(
        const float4* __restrict__ pre4, const float4* __restrict__ cur4,
        const float* __restrict__ ups,
        const unsigned* __restrict__ c2p,
        float* __restrict__ out) {
    __shared__ float4 sc[TILE_B];
    const int tid  = threadIdx.x;
    const int lane = tid & 63;
    const int w    = tid >> 6;                 // 0..3
    const int i0   = blockIdx.x * 16 + w * 4;  // this wave's 4 pre points

    float4 pq[4];
#pragma unroll
    for (int t = 0; t < 4; ++t) pq[t] = pre4[i0 + t];   // (-2p, |p|^2)

    unsigned ld[4], li[4];
    float    t8[4];
#pragma unroll
    for (int t = 0; t < 4; ++t) {
        ld[t] = MAPPED_INF; li[t] = 0u; t8[t] = __int_as_float(0x7F800000);
    }

    for (int tile = 0; tile < N_CUR; tile += TILE_B) {
        __syncthreads();
        for (int k = tid; k < TILE_B; k += 256) sc[k] = cur4[tile + k];
        __syncthreads();

        for (int s = 0; s < TILE_B; s += 256) {
            float4 c0 = sc[s +       lane];
            float4 c1 = sc[s +  64 + lane];
            float4 c2 = sc[s + 128 + lane];
            float4 c3 = sc[s + 192 + lane];
            float d[4][4];
#pragma unroll
            for (int t = 0; t < 4; ++t) {
                d[t][0] = fmaf(pq[t].x, c0.x, fmaf(pq[t].y, c0.y, fmaf(pq[t].z, c0.z, c0.w)));
                d[t][1] = fmaf(pq[t].x, c1.x, fmaf(pq[t].y, c1.y, fmaf(pq[t].z, c1.z, c1.w)));
                d[t][2] = fmaf(pq[t].x, c2.x, fmaf(pq[t].y, c2.y, fmaf(pq[t].z, c2.z, c2.w)));
                d[t][3] = fmaf(pq[t].x, c3.x, fmaf(pq[t].y, c3.y, fmaf(pq[t].z, c3.z, c3.w)));
            }
            bool ev = false;
#pragma unroll
            for (int t = 0; t < 4; ++t) {
                float dm = fminf(fminf(d[t][0], d[t][1]), fminf(d[t][2], d[t][3]));
                ev = ev || (dm < t8[t]);
            }
            if (__any(ev)) {
                int base = tile + s;
#pragma unroll
                for (int t = 0; t < 4; ++t) {
#pragma unroll
                    for (int k = 0; k < 4; ++k) {
                        unsigned long long m = __ballot(d[t][k] < t8[t]);
                        while (m) {
                            int src = __ffsll((long long)m) - 1;
                            float fd = __uint_as_float(
                                shfl_u32(__float_as_uint(d[t][k]), src));
                            unsigned kd = key_of(fd);
                            unsigned kj = (unsigned)(base + 64 * k + src);
                            unsigned ud = shfl_up1_u32(ld[t]);
                            unsigned uj = shfl_up1_u32(li[t]);
                            if (lane == 0) ud = 0u;   // nothing below lane 0
                            bool hi = kd < ud, lo = kd < ld[t];
                            ld[t] = hi ? ud : (lo ? kd : ld[t]);
                            li[t] = hi ? uj : (lo ? kj : li[t]);
                            t8[t] = float_of_key(shfl_u32(ld[t], 7));
                            m = (m & (m - 1)) & __ballot(d[t][k] < t8[t]);
                        }
                    }
                }
            }
        }
    }

    // finalize: lane group g = lane>>3 (g<4) handles pre i0+g, slot lane&7.
    unsigned jt[4];
#pragma unroll
    for (int t = 0; t < 4; ++t) jt[t] = shfl_u32(li[t], lane & 7);
    const int g = lane >> 3;
    unsigned j = (g == 0) ? jt[0] : (g == 1) ? jt[1] : (g == 2) ? jt[2] : jt[3];

    float contrib = 0.f;
    if (lane < 32) {
        float4 c = cur4[j];
        float4 p = (g == 0) ? pq[0] : (g == 1) ? pq[1] : (g == 2) ? pq[2] : pq[3];
        float px = -0.5f * p.x, py = -0.5f * p.y, pz = -0.5f * p.z;
        float dx = c.x - px, dy = c.y - py, dz = c.z - pz;
        float dsq = fmaf(dx, dx, fmaf(dy, dy, dz * dz));
        contrib = (c2p[j] == (unsigned)(i0 + g)) ? sqrtf(dsq) : 0.f;
    }
    contrib += __shfl_xor(contrib, 1);
    contrib += __shfl_xor(contrib, 2);
    contrib += __shfl_xor(contrib, 4);
    if (lane < 32 && (lane & 7) == 0) out[i0 + g] = contrib / ups[i0 + g];
}

// ---------- launch ----------
extern "C" void kernel_launch(void* const* d_in, const int* in_sizes, int n_in,
                              void* d_out, int out_size, void* d_ws, size_t ws_size,
                              hipStream_t stream) {
    const float* pre = (const float*)d_in[0];   // (1,3,8192)
    const float* cur = (const float*)d_in[1];   // (1,3,16384)
    const float* ups = (const float*)d_in[2];   // (1,8192)
    float* out = (float*)d_out;                 // (1,8192)

    char* ws = (char*)d_ws;
    unsigned* c2p  = (unsigned*)ws;                   //  64 KB
    float4*   pre4 = (float4*)(ws + 65536);           // 128 KB
    float4*   cur4 = (float4*)(ws + 65536 + 131072);  // 256 KB

    prep_kernel<<<N_CUR / 256, 256, 0, stream>>>(pre, cur, pre4, cur4);

    cur2pre_kernel<<<N_CUR / 16, 256, 0, stream>>>(pre4, cur4, c2p);

    knn_finalize_kernel<<<N_PRE / 16, 256, 0, stream>>>(pre4, cur4, ups, c2p, out);
}

// Round 6
// 149.453 us; speedup vs baseline: 1.0936x; 1.0936x over previous
//
#include <hip/hip_runtime.h>

// Problem constants (fixed by reference setup_inputs)
#define N_PRE 8192
#define N_CUR 16384
#define KNN   8

// Workspace layout (bytes):
//   [0,    64K) : c2p  u32[N_CUR]     nearest-pre index per cur point
//   [64K, 192K) : pre4 float4[N_PRE]  (-2px, -2py, -2pz, |p|^2)
//   [192K,448K) : cur4 float4[N_CUR]  ( cx,   cy,   cz,  |c|^2)
//
// Comparator trick: for a fixed query q, ordering by true sqdist equals
// ordering by (|cand|^2 - 2 cand.q)  -> 3 FMA per candidate.
//   A (query=cur, cand=pre): d = pre4.w + dot(pre4.xyz, cur.xyz)
//   B (query=pre, cand=cur): d = cur4.w + dot(pre4.xyz, cur.xyz)
// d can be NEGATIVE -> monotone float->u32 key map on (rare) insert events.

#define MAPPED_INF 0xFF800000u  // monotone key of +inf (empty-slot sentinel)

__device__ __forceinline__ unsigned key_of(float d) {
    unsigned b = __float_as_uint(d);
    return b ^ (0x80000000u | (unsigned)((int)b >> 31));
}
__device__ __forceinline__ float float_of_key(unsigned k) {
    unsigned b = (k & 0x80000000u) ? (k ^ 0x80000000u) : ~k;
    return __uint_as_float(b);
}
__device__ __forceinline__ unsigned shfl_u32(unsigned x, int src) {
    return (unsigned)__shfl((int)x, src);
}
__device__ __forceinline__ unsigned shfl_up1_u32(unsigned x) {
    return (unsigned)__shfl_up((int)x, 1);
}

// ---------- prep: pack comparator-form coords ----------
__global__ __launch_bounds__(256) void prep_kernel(
        const float* __restrict__ pre, const float* __restrict__ cur,
        float4* __restrict__ pre4, float4* __restrict__ cur4) {
    int i = blockIdx.x * 256 + threadIdx.x;
    if (i < N_CUR) {
        float x = cur[i], y = cur[N_CUR + i], z = cur[2 * N_CUR + i];
        cur4[i] = make_float4(x, y, z, fmaf(x, x, fmaf(y, y, z * z)));
    }
    if (i < N_PRE) {
        float x = pre[i], y = pre[N_PRE + i], z = pre[2 * N_PRE + i];
        pre4[i] = make_float4(-2.f * x, -2.f * y, -2.f * z,
                              fmaf(x, x, fmaf(y, y, z * z)));
    }
}

// ---------- Kernel A: cur2pre argmin (ballot-event scheme) ----------
// 1024-thr blocks, 16 waves; wave owns Q=4 cur queries; candidates per lane
// from LDS tile. Fast path per step: 1 ds_read_b128 + 4x(3 FMA + 1 cmp).
// Wave-uniform running best (key<<32|idx); event path = u64 butterfly min
// (lowest idx on ties). Records decay ~H(steps) -> events are rare.
#define TILE_A 2048

__global__ __launch_bounds__(1024) void cur2pre_kernel(
        const float4* __restrict__ pre4, const float4* __restrict__ cur4,
        unsigned* __restrict__ c2p) {
    __shared__ float4 sp[TILE_A];
    const int tid  = threadIdx.x;
    const int lane = tid & 63;
    const int w    = tid >> 6;                 // 0..15
    const int j0   = blockIdx.x * 64 + w * 4;  // this wave's 4 cur points

    const float4 c0 = cur4[j0 + 0];
    const float4 c1 = cur4[j0 + 1];
    const float4 c2 = cur4[j0 + 2];
    const float4 c3 = cur4[j0 + 3];

    const float INF = __int_as_float(0x7F800000);
    float t0 = INF, t1 = INF, t2 = INF, t3 = INF;   // current best (uniform)
    unsigned long long bv0 = ~0ull, bv1 = ~0ull, bv2 = ~0ull, bv3 = ~0ull;

    for (int tile = 0; tile < N_PRE; tile += TILE_A) {
        __syncthreads();
        for (int k = tid; k < TILE_A; k += 1024) sp[k] = pre4[tile + k];
        __syncthreads();

        for (int s = 0; s < TILE_A; s += 64) {
            float4 p = sp[s + lane];
            unsigned idx = (unsigned)(tile + s + lane);
            float d0 = fmaf(p.x, c0.x, fmaf(p.y, c0.y, fmaf(p.z, c0.z, p.w)));
            float d1 = fmaf(p.x, c1.x, fmaf(p.y, c1.y, fmaf(p.z, c1.z, p.w)));
            float d2 = fmaf(p.x, c2.x, fmaf(p.y, c2.y, fmaf(p.z, c2.z, p.w)));
            float d3 = fmaf(p.x, c3.x, fmaf(p.y, c3.y, fmaf(p.z, c3.z, p.w)));

            unsigned long long m0 = __ballot(d0 < t0);
            unsigned long long m1 = __ballot(d1 < t1);
            unsigned long long m2 = __ballot(d2 < t2);
            unsigned long long m3 = __ballot(d3 < t3);

            if (m0 | m1 | m2 | m3) {   // rare (record-low decay)
                if (m0) {
                    unsigned long long v =
                        (((unsigned long long)key_of(d0)) << 32) | idx;
#pragma unroll
                    for (int off = 32; off > 0; off >>= 1) {
                        unsigned long long o = __shfl_xor((unsigned long long)v, off);
                        v = (o < v) ? o : v;
                    }
                    if (v < bv0) { bv0 = v; t0 = float_of_key((unsigned)(bv0 >> 32)); }
                }
                if (m1) {
                    unsigned long long v =
                        (((unsigned long long)key_of(d1)) << 32) | idx;
#pragma unroll
                    for (int off = 32; off > 0; off >>= 1) {
                        unsigned long long o = __shfl_xor((unsigned long long)v, off);
                        v = (o < v) ? o : v;
                    }
                    if (v < bv1) { bv1 = v; t1 = float_of_key((unsigned)(bv1 >> 32)); }
                }
                if (m2) {
                    unsigned long long v =
                        (((unsigned long long)key_of(d2)) << 32) | idx;
#pragma unroll
                    for (int off = 32; off > 0; off >>= 1) {
                        unsigned long long o = __shfl_xor((unsigned long long)v, off);
                        v = (o < v) ? o : v;
                    }
                    if (v < bv2) { bv2 = v; t2 = float_of_key((unsigned)(bv2 >> 32)); }
                }
                if (m3) {
                    unsigned long long v =
                        (((unsigned long long)key_of(d3)) << 32) | idx;
#pragma unroll
                    for (int off = 32; off > 0; off >>= 1) {
                        unsigned long long o = __shfl_xor((unsigned long long)v, off);
                        v = (o < v) ? o : v;
                    }
                    if (v < bv3) { bv3 = v; t3 = float_of_key((unsigned)(bv3 >> 32)); }
                }
            }
        }
    }

    if (lane == 0) {
        c2p[j0 + 0] = (unsigned)(bv0 & 0xFFFFFFFFull);
        c2p[j0 + 1] = (unsigned)(bv1 & 0xFFFFFFFFull);
        c2p[j0 + 2] = (unsigned)(bv2 & 0xFFFFFFFFull);
        c2p[j0 + 3] = (unsigned)(bv3 & 0xFFFFFFFFull);
    }
}

// ---------- Kernel B: per-pre top-8 + masked mean ----------
// Round-4 proven shape (1024-thr, 16 waves, P=2) + CPL=2: two independent
// ds_read_b128 per step for latency overlap. Fast path per step (256 pair
// evals): 2 reads + 4x(3 FMA) + 4 cmp. Events: ascending-idx shift-insert
// into lanes-0..7 sorted (key,idx) list with re-ballot pruning.
#define TILE_B 2048

__global__ __launch_bounds__(1024) void knn_finalize_kernel(
        const float4* __restrict__ pre4, const float4* __restrict__ cur4,
        const float* __restrict__ ups,
        const unsigned* __restrict__ c2p,
        float* __restrict__ out) {
    __shared__ float4 sc[TILE_B];
    const int tid  = threadIdx.x;
    const int lane = tid & 63;
    const int w    = tid >> 6;                 // 0..15
    const int i0   = blockIdx.x * 32 + w * 2;  // this wave's two pre points
    const int i1   = i0 + 1;

    const float4 p0 = pre4[i0];   // (-2p, |p|^2)
    const float4 p1 = pre4[i1];

    unsigned ld0 = MAPPED_INF, li0 = 0u;
    unsigned ld1 = MAPPED_INF, li1 = 0u;
    float t80 = __int_as_float(0x7F800000);
    float t81 = t80;

    for (int tile = 0; tile < N_CUR; tile += TILE_B) {
        __syncthreads();
        for (int k = tid; k < TILE_B; k += 1024) sc[k] = cur4[tile + k];
        __syncthreads();

        for (int s = 0; s < TILE_B; s += 128) {
            float4 ca = sc[s + lane];
            float4 cb = sc[s + 64 + lane];
            float d0a = fmaf(p0.x, ca.x, fmaf(p0.y, ca.y, fmaf(p0.z, ca.z, ca.w)));
            float d0b = fmaf(p0.x, cb.x, fmaf(p0.y, cb.y, fmaf(p0.z, cb.z, cb.w)));
            float d1a = fmaf(p1.x, ca.x, fmaf(p1.y, ca.y, fmaf(p1.z, ca.z, ca.w)));
            float d1b = fmaf(p1.x, cb.x, fmaf(p1.y, cb.y, fmaf(p1.z, cb.z, cb.w)));

            unsigned long long m0a = __ballot(d0a < t80);
            unsigned long long m0b = __ballot(d0b < t80);
            unsigned long long m1a = __ballot(d1a < t81);
            unsigned long long m1b = __ballot(d1b < t81);

            if (m0a | m0b | m1a | m1b) {
                int base = tile + s;
                // pre i0, candidates [base, base+64) then [base+64, base+128)
                while (m0a) {
                    int src = __ffsll((long long)m0a) - 1;
                    unsigned kd = key_of(__uint_as_float(
                        shfl_u32(__float_as_uint(d0a), src)));
                    unsigned kj = (unsigned)(base + src);
                    unsigned ud = shfl_up1_u32(ld0);
                    unsigned uj = shfl_up1_u32(li0);
                    if (lane == 0) ud = 0u;
                    bool hi = kd < ud, lo = kd < ld0;
                    ld0 = hi ? ud : (lo ? kd : ld0);
                    li0 = hi ? uj : (lo ? kj : li0);
                    t80 = float_of_key(shfl_u32(ld0, 7));
                    m0a = (m0a & (m0a - 1)) & __ballot(d0a < t80);
                }
                while (m0b) {
                    int src = __ffsll((long long)m0b) - 1;
                    unsigned kd = key_of(__uint_as_float(
                        shfl_u32(__float_as_uint(d0b), src)));
                    unsigned kj = (unsigned)(base + 64 + src);
                    unsigned ud = shfl_up1_u32(ld0);
                    unsigned uj = shfl_up1_u32(li0);
                    if (lane == 0) ud = 0u;
                    bool hi = kd < ud, lo = kd < ld0;
                    ld0 = hi ? ud : (lo ? kd : ld0);
                    li0 = hi ? uj : (lo ? kj : li0);
                    t80 = float_of_key(shfl_u32(ld0, 7));
                    m0b = (m0b & (m0b - 1)) & __ballot(d0b < t80);
                }
                while (m1a) {
                    int src = __ffsll((long long)m1a) - 1;
                    unsigned kd = key_of(__uint_as_float(
                        shfl_u32(__float_as_uint(d1a), src)));
                    unsigned kj = (unsigned)(base + src);
                    unsigned ud = shfl_up1_u32(ld1);
                    unsigned uj = shfl_up1_u32(li1);
                    if (lane == 0) ud = 0u;
                    bool hi = kd < ud, lo = kd < ld1;
                    ld1 = hi ? ud : (lo ? kd : ld1);
                    li1 = hi ? uj : (lo ? kj : li1);
                    t81 = float_of_key(shfl_u32(ld1, 7));
                    m1a = (m1a & (m1a - 1)) & __ballot(d1a < t81);
                }
                while (m1b) {
                    int src = __ffsll((long long)m1b) - 1;
                    unsigned kd = key_of(__uint_as_float(
                        shfl_u32(__float_as_uint(d1b), src)));
                    unsigned kj = (unsigned)(base + 64 + src);
                    unsigned ud = shfl_up1_u32(ld1);
                    unsigned uj = shfl_up1_u32(li1);
                    if (lane == 0) ud = 0u;
                    bool hi = kd < ud, lo = kd < ld1;
                    ld1 = hi ? ud : (lo ? kd : ld1);
                    li1 = hi ? uj : (lo ? kj : li1);
                    t81 = float_of_key(shfl_u32(ld1, 7));
                    m1b = (m1b & (m1b - 1)) & __ballot(d1b < t81);
                }
            }
        }
    }

    // finalize: lanes 0..7 -> i0's list, lanes 8..15 -> i1's.
    unsigned ja = shfl_u32(li0, lane & 7);
    unsigned jb = shfl_u32(li1, lane & 7);
    unsigned j  = (lane < 8) ? ja : jb;

    float contrib = 0.f;
    if (lane < 16) {
        float4 c = cur4[j];
        float px = -0.5f * ((lane < 8) ? p0.x : p1.x);
        float py = -0.5f * ((lane < 8) ? p0.y : p1.y);
        float pz = -0.5f * ((lane < 8) ? p0.z : p1.z);
        float dx = c.x - px, dy = c.y - py, dz = c.z - pz;
        float dsq = fmaf(dx, dx, fmaf(dy, dy, dz * dz));
        unsigned owner = c2p[j];
        unsigned iexp  = (lane < 8) ? (unsigned)i0 : (unsigned)i1;
        contrib = (owner == iexp) ? sqrtf(dsq) : 0.f;
    }
    contrib += __shfl_xor(contrib, 1);
    contrib += __shfl_xor(contrib, 2);
    contrib += __shfl_xor(contrib, 4);
    if (lane == 0) out[i0] = contrib / ups[i0];
    if (lane == 8) out[i1] = contrib / ups[i1];
}

// ---------- launch ----------
extern "C" void kernel_launch(void* const* d_in, const int* in_sizes, int n_in,
                              void* d_out, int out_size, void* d_ws, size_t ws_size,
                              hipStream_t stream) {
    const float* pre = (const float*)d_in[0];   // (1,3,8192)
    const float* cur = (const float*)d_in[1];   // (1,3,16384)
    const float* ups = (const float*)d_in[2];   // (1,8192)
    float* out = (float*)d_out;                 // (1,8192)

    char* ws = (char*)d_ws;
    unsigned* c2p  = (unsigned*)ws;                   //  64 KB
    float4*   pre4 = (float4*)(ws + 65536);           // 128 KB
    float4*   cur4 = (float4*)(ws + 65536 + 131072);  // 256 KB

    prep_kernel<<<N_CUR / 256, 256, 0, stream>>>(pre, cur, pre4, cur4);

    cur2pre_kernel<<<N_CUR / 64, 1024, 0, stream>>>(pre4, cur4, c2p);

    knn_finalize_kernel<<<N_PRE / 32, 1024, 0, stream>>>(pre4, cur4, ups, c2p, out);
}